// Round 4
// baseline (817.036 us; speedup 1.0000x reference)
//
#include <hip/hip_runtime.h>
#include <hip/hip_bf16.h>
#include <math.h>

// Problem constants
#define B_SZ 8
#define N_SZ 4096
#define C_SZ 128
#define K_SZ 16
#define NPOINT 1024            // N / POOL_RATE

// FPS config: 512 threads (8 waves, 2 per SIMD), 8 points per thread
#define FPS_T 512
#define FPS_PAIRS 4            // 4 float2-pairs = 8 points per thread
#define TR_BLOCKS 2048         // transpose companion blocks (2 tiles each)

typedef float vf2 __attribute__((ext_vector_type(2)));

// ---------------------------------------------------------------------------
// Wave64 arg-select via a single u64-key DPP MIN chain.
// ikey = (~dist_bits << 32) | n : dist >= 0 so ~bits is monotone-decreasing
// in dist => min ikey == max dist; ties => min n (numpy first-argmax).
// bound_ctrl=0 with old=self: invalid lanes contribute self (no-op for min).
// Result valid in lane 63.
// ---------------------------------------------------------------------------
template <int CTRL>
__device__ __forceinline__ unsigned long long dpp_kmin_step(unsigned long long k) {
    const int lo = (int)(unsigned)k;
    const int hi = (int)(unsigned)(k >> 32);
    const unsigned lo2 = (unsigned)__builtin_amdgcn_update_dpp(lo, lo, CTRL, 0xF, 0xF, false);
    const unsigned hi2 = (unsigned)__builtin_amdgcn_update_dpp(hi, hi, CTRL, 0xF, 0xF, false);
    const unsigned long long k2 = ((unsigned long long)hi2 << 32) | (unsigned long long)lo2;
    return (k2 < k) ? k2 : k;
}
__device__ __forceinline__ unsigned long long wave_kmin63(unsigned long long k) {
    k = dpp_kmin_step<0x111>(k);  // row_shr:1
    k = dpp_kmin_step<0x112>(k);  // row_shr:2
    k = dpp_kmin_step<0x114>(k);  // row_shr:4
    k = dpp_kmin_step<0x118>(k);  // row_shr:8
    k = dpp_kmin_step<0x142>(k);  // row_bcast:15
    k = dpp_kmin_step<0x143>(k);  // row_bcast:31
    return k;
}

// ---------------------------------------------------------------------------
// Kernel A: blocks 0..7 run FPS (one per batch); blocks 8.. run the
// feature-map transpose (B,C,N)->(B*N,C) concurrently on the idle CUs.
// The transpose path aliases the FPS xyz LDS buffer as its tile storage.
// ---------------------------------------------------------------------------
__global__ __launch_bounds__(FPS_T) void fps_fused(
        const float* __restrict__ verts,   // (B, 3, N)
        const float* __restrict__ fm,      // (B, C, N)
        float* __restrict__ fmT,           // (B*N, C)
        float* __restrict__ out_vp,        // (B, 3, NPOINT)
        int* __restrict__ cents)           // (B, NPOINT)
{
#pragma clang fp contract(off)
#pragma clang fp reassociate(off)
    __shared__ float4 sp[N_SZ];                       // 64 KB xyz (w unused)
    __shared__ int    scent[NPOINT];                  //  4 KB
    __shared__ unsigned long long slot[4];

    const int tid = threadIdx.x;

    if (blockIdx.x >= B_SZ) {
        // ---------------- transpose path: 2 x (32x32) tiles per block ------
        float* tile = (float*)sp;          // [2][32][33] floats, aliased
        const int half = tid >> 8;         // 0 or 1
        const int t    = tid & 255;
        const int tx   = t & 31;
        const int ty   = t >> 5;           // 0..7
        const int g    = 2 * (blockIdx.x - B_SZ) + half;   // global tile id
        const int b    = g >> 9;                           // 512 tiles/batch
        const int r    = g & 511;
        const int n0   = (r & 127) * 32;
        const int c0   = (r >> 7) * 32;
        float* tl = tile + half * (32 * 33);
        const float* p = fm + (size_t)b * C_SZ * N_SZ;
#pragma unroll
        for (int i = 0; i < 4; i++) {
            tl[(ty + i * 8) * 33 + tx] = p[(size_t)(c0 + ty + i * 8) * N_SZ + n0 + tx];
        }
        __syncthreads();
        float* q = fmT + (size_t)b * N_SZ * C_SZ;
#pragma unroll
        for (int i = 0; i < 4; i++) {
            q[(size_t)(n0 + ty + i * 8) * C_SZ + c0 + tx] = tl[tx * 33 + ty + i * 8];
        }
        return;
    }

    // -------------------------------- FPS path ----------------------------
    const int b    = blockIdx.x;
    const int lane = tid & 63;
    const float* vb = verts + (size_t)b * 3 * N_SZ;

    // pair p covers global points n = tid + (2p)*512 and n + 512
    vf2 px[FPS_PAIRS], py[FPS_PAIRS], pz[FPS_PAIRS], dd[FPS_PAIRS];
#pragma unroll
    for (int p = 0; p < FPS_PAIRS; p++) {
        const int n0 = tid + (2 * p) * FPS_T;
        const int n1 = n0 + FPS_T;
        const float x0 = vb[n0],            x1 = vb[n1];
        const float y0 = vb[N_SZ + n0],     y1 = vb[N_SZ + n1];
        const float z0 = vb[2 * N_SZ + n0], z1 = vb[2 * N_SZ + n1];
        px[p] = (vf2){x0, x1};
        py[p] = (vf2){y0, y1};
        pz[p] = (vf2){z0, z1};
        dd[p] = (vf2){1e10f, 1e10f};
        sp[n0] = make_float4(x0, y0, z0, 0.0f);
        sp[n1] = make_float4(x1, y1, z1, 0.0f);
    }
    if (tid < 4) slot[tid] = ~0ull;
    __syncthreads();

    int ci = 0;
    float4 c0 = sp[0];
    float cx = c0.x, cy = c0.y, cz = c0.z;

    for (int i = 0; i < NPOINT; i++) {
        if (tid == 0) scent[i] = ci;

        const vf2 cx2 = (vf2){cx, cx};
        const vf2 cy2 = (vf2){cy, cy};
        const vf2 cz2 = (vf2){cz, cz};

        float bv = -1.0f;
        int   bj = 0;
#pragma unroll
        for (int p = 0; p < FPS_PAIRS; p++) {
            const vf2 dx = px[p] - cx2;
            const vf2 dy = py[p] - cy2;
            const vf2 dz = pz[p] - cz2;
            vf2 s = dx * dx + dy * dy;   // contract off => mul,mul,add (exact)
            s = s + dz * dz;
            vf2 d;
            d.x = fminf(dd[p].x, s.x);
            d.y = fminf(dd[p].y, s.y);
            dd[p] = d;
            // strictly-greater keeps lowest index (j ascending => n ascending)
            if (d.x > bv) { bv = d.x; bj = 2 * p; }
            if (d.y > bv) { bv = d.y; bj = 2 * p + 1; }
        }
        // global point index n = tid + bj*512
        const unsigned n = (unsigned)(tid + (bj << 9));
        unsigned long long key =
            ((unsigned long long)(~__float_as_uint(bv)) << 32) |
            (unsigned long long)n;

        key = wave_kmin63(key);
        if (lane == 63) atomicMin(&slot[i & 3], key);
        if (tid == 0)   slot[(i + 2) & 3] = ~0ull;   // reset for iter i+2
        __syncthreads();

        const unsigned long long kk = slot[i & 3];
        ci = (int)(unsigned)kk;
        const float4 c = sp[ci];
        cx = c.x; cy = c.y; cz = c.z;
    }
    __syncthreads();

    // epilogue: coalesced writes of cents + vertices_pool
    for (int i = tid; i < NPOINT; i += FPS_T) {
        const int cc = scent[i];
        const float4 v = sp[cc];
        cents[b * NPOINT + i] = cc;
        out_vp[(b * 3 + 0) * NPOINT + i] = v.x;
        out_vp[(b * 3 + 1) * NPOINT + i] = v.y;
        out_vp[(b * 3 + 2) * NPOINT + i] = v.z;
    }
}

// ---------------------------------------------------------------------------
// Kernel B: gather+maxpool selected rows AND transpose to (B, C, NPOINT).
// 16 waves per block; wave w pools point j0+w (64 lanes x float2 = 128 ch),
// stages the 16x128 tile in LDS, then writes channel-major 64B segments.
// ---------------------------------------------------------------------------
#define GT_J 16
__global__ __launch_bounds__(1024) void pool_gather_t(
        const float* __restrict__ fmT,     // (B*N, C)
        const int* __restrict__ idx,       // (B*N*K), values in [0, B*N)
        const int* __restrict__ cents,     // (B*NPOINT)
        float* __restrict__ out_fp)        // (B, C, NPOINT)
{
    __shared__ float tile[C_SZ][GT_J + 1];
    const int tid  = threadIdx.x;
    const int lane = tid & 63;
    const int w    = tid >> 6;
    const int j0   = blockIdx.x * GT_J;    // global pooled-point base
    const int gp   = j0 + w;
    const int b    = gp >> 10;             // NPOINT = 1024
    const int ci   = cents[gp];
    const int* ip  = idx + ((size_t)(b * N_SZ + ci)) * K_SZ;
    const float2* src = (const float2*)fmT;

    float2 acc = make_float2(-INFINITY, -INFINITY);
#pragma unroll
    for (int k = 0; k < K_SZ; k++) {
        const int p = ip[k];
        const float2 v = src[(size_t)p * (C_SZ / 2) + lane];
        acc.x = fmaxf(acc.x, v.x);
        acc.y = fmaxf(acc.y, v.y);
    }
    tile[2 * lane][w]     = acc.x;
    tile[2 * lane + 1][w] = acc.y;
    __syncthreads();

    float* q = out_fp + (size_t)b * C_SZ * NPOINT + (j0 & (NPOINT - 1));
#pragma unroll
    for (int it = 0; it < 2; it++) {
        const int e  = tid + it * 1024;
        const int c  = e >> 4;
        const int jj = e & (GT_J - 1);
        q[(size_t)c * NPOINT + jj] = tile[c][jj];
    }
}

// ---------------------------------------------------------------------------
extern "C" void kernel_launch(void* const* d_in, const int* in_sizes, int n_in,
                              void* d_out, int out_size, void* d_ws, size_t ws_size,
                              hipStream_t stream) {
    const float* verts = (const float*)d_in[0];   // (B,3,N) f32
    const float* fm    = (const float*)d_in[1];   // (B,C,N) f32
    const int*   idx   = (const int*)d_in[2];     // (B*N*K) i32

    float* out    = (float*)d_out;
    float* out_vp = out;                               // B*3*NPOINT = 24576
    float* out_fp = out + (size_t)B_SZ * 3 * NPOINT;   // B*C*NPOINT

    char* ws = (char*)d_ws;
    float* fmT   = (float*)ws;                                     // 16 MB
    int*   cents = (int*)(ws + (size_t)B_SZ * N_SZ * C_SZ * 4);    // 32 KB

    fps_fused<<<B_SZ + TR_BLOCKS, FPS_T, 0, stream>>>(verts, fm, fmT, out_vp, cents);
    pool_gather_t<<<(B_SZ * NPOINT) / GT_J, 1024, 0, stream>>>(fmT, idx, cents, out_fp);
}

// Round 6
// 758.590 us; speedup vs baseline: 1.0770x; 1.0770x over previous
//
#include <hip/hip_runtime.h>
#include <hip/hip_bf16.h>
#include <math.h>

// Problem constants
#define B_SZ 8
#define N_SZ 4096
#define C_SZ 128
#define K_SZ 16
#define NPOINT 1024            // N / POOL_RATE

// FPS config: 512 threads (8 waves, 2 per SIMD), 8 points per thread
#define FPS_T 512
#define FPS_PAIRS 4            // 4 float2-pairs = 8 points per thread

typedef float vf2 __attribute__((ext_vector_type(2)));

// Forced packed-fp32 ops (per-element IEEE, bit-exact vs scalar numpy ops).
// NOTE (gfx950): VOP3P packed fp32 has ONLY add/mul/fma — v_pk_min_f32 /
// v_pk_max_f32 do not exist (R5 compile error). min/max stay scalar.
__device__ __forceinline__ vf2 pk_add(vf2 a, vf2 b) {
    vf2 d; asm("v_pk_add_f32 %0, %1, %2" : "=v"(d) : "v"(a), "v"(b)); return d;
}
__device__ __forceinline__ vf2 pk_mul(vf2 a, vf2 b) {
    vf2 d; asm("v_pk_mul_f32 %0, %1, %2" : "=v"(d) : "v"(a), "v"(b)); return d;
}

// ---------------------------------------------------------------------------
// Wave64 argmax via a single u64-key DPP max chain (proven exact in R2/R3).
// key = (dist_bits << 32) | (4095 - n): max key == max dist, min n on ties.
// bound_ctrl=1 feeds 0 into invalid lanes (never beats a real key).
// Result valid in lane 63.
// ---------------------------------------------------------------------------
template <int CTRL>
__device__ __forceinline__ unsigned long long dpp_kmax_step(unsigned long long k) {
    const unsigned lo = (unsigned)k;
    const unsigned hi = (unsigned)(k >> 32);
    const unsigned lo2 = (unsigned)__builtin_amdgcn_update_dpp(0, (int)lo, CTRL, 0xF, 0xF, true);
    const unsigned hi2 = (unsigned)__builtin_amdgcn_update_dpp(0, (int)hi, CTRL, 0xF, 0xF, true);
    const unsigned long long k2 = ((unsigned long long)hi2 << 32) | (unsigned long long)lo2;
    return (k2 > k) ? k2 : k;
}
__device__ __forceinline__ unsigned long long wave_kmax63(unsigned long long k) {
    k = dpp_kmax_step<0x111>(k);  // row_shr:1
    k = dpp_kmax_step<0x112>(k);  // row_shr:2
    k = dpp_kmax_step<0x114>(k);  // row_shr:4
    k = dpp_kmax_step<0x118>(k);  // row_shr:8
    k = dpp_kmax_step<0x142>(k);  // row_bcast:15
    k = dpp_kmax_step<0x143>(k);  // row_bcast:31
    return k;
}
__device__ __forceinline__ unsigned long long kmax2(unsigned long long a,
                                                   unsigned long long b) {
    return a > b ? a : b;
}

// ---------------------------------------------------------------------------
// Kernel 1: transpose feature_map (B, C, N) -> fmT (B*N, C)
// ---------------------------------------------------------------------------
__global__ void transpose_fm(const float* __restrict__ fm, float* __restrict__ fmT) {
    __shared__ float tile[32][33];
    const int b  = blockIdx.z;
    const int c0 = blockIdx.y * 32;
    const int n0 = blockIdx.x * 32;
    const int tx = threadIdx.x;   // 0..31
    const int ty = threadIdx.y;   // 0..7
    const float* p = fm + (size_t)b * C_SZ * N_SZ;
#pragma unroll
    for (int i = 0; i < 4; i++) {
        tile[ty + i * 8][tx] = p[(size_t)(c0 + ty + i * 8) * N_SZ + n0 + tx];
    }
    __syncthreads();
    float* q = fmT + (size_t)b * N_SZ * C_SZ;
#pragma unroll
    for (int i = 0; i < 4; i++) {
        q[(size_t)(n0 + ty + i * 8) * C_SZ + c0 + tx] = tile[tx][ty + i * 8];
    }
}

// ---------------------------------------------------------------------------
// Kernel 2: FPS, one block (512 threads, 8 waves) per batch.
// Bit-exact numpy semantics: d=((x-cx)^2+(y-cy)^2)+(z-cz)^2 per-op rounding.
// Subtraction realized as x + (-cx): IEEE-identical to x - cx, enabling
// v_pk_add. One barrier per iter; u64-key DPP argmax; distance block in
// forced packed-fp32 (add/mul); argmax index recovered by a post-loop
// reverse scan (keeps lowest index on ties). No global traffic in the loop.
// ---------------------------------------------------------------------------
__global__ __launch_bounds__(FPS_T) void fps_kernel(
        const float* __restrict__ verts,   // (B, 3, N)
        float* __restrict__ out_vp,        // (B, 3, NPOINT)
        int* __restrict__ cents)           // (B, NPOINT)
{
#pragma clang fp contract(off)
#pragma clang fp reassociate(off)
    __shared__ float4 sp[N_SZ];                       // 64 KB xyz (w unused)
    __shared__ int    scent[NPOINT];                  //  4 KB
    __shared__ alignas(16) unsigned long long ckey[2][8];

    const int b    = blockIdx.x;
    const int tid  = threadIdx.x;
    const int lane = tid & 63;
    const int wid  = tid >> 6;
    const float* vb = verts + (size_t)b * 3 * N_SZ;

    // pair p covers global points n = tid + (2p)*512 and n + 512
    vf2 px[FPS_PAIRS], py[FPS_PAIRS], pz[FPS_PAIRS], dd[FPS_PAIRS];
#pragma unroll
    for (int p = 0; p < FPS_PAIRS; p++) {
        const int n0 = tid + (2 * p) * FPS_T;
        const int n1 = n0 + FPS_T;
        const float x0 = vb[n0],            x1 = vb[n1];
        const float y0 = vb[N_SZ + n0],     y1 = vb[N_SZ + n1];
        const float z0 = vb[2 * N_SZ + n0], z1 = vb[2 * N_SZ + n1];
        px[p] = (vf2){x0, x1};
        py[p] = (vf2){y0, y1};
        pz[p] = (vf2){z0, z1};
        dd[p] = (vf2){1e10f, 1e10f};
        sp[n0] = make_float4(x0, y0, z0, 0.0f);
        sp[n1] = make_float4(x1, y1, z1, 0.0f);
    }
    __syncthreads();

    int ci = 0;
    float4 c0 = sp[0];
    float cx = c0.x, cy = c0.y, cz = c0.z;

    for (int i = 0; i < NPOINT; i++) {
        if (tid == 0) scent[i] = ci;

        // exact negation (sign-flip, no rounding)
        const float nx = -cx, ny = -cy, nz = -cz;
        const vf2 ncx = (vf2){nx, nx};
        const vf2 ncy = (vf2){ny, ny};
        const vf2 ncz = (vf2){nz, nz};

        float m0 = -1.0f, m1 = -1.0f;      // running max (two halves)
#pragma unroll
        for (int p = 0; p < FPS_PAIRS; p++) {
            const vf2 dx = pk_add(px[p], ncx);     // == px - cx (exact)
            const vf2 dy = pk_add(py[p], ncy);
            const vf2 dz = pk_add(pz[p], ncz);
            const vf2 xx = pk_mul(dx, dx);
            const vf2 yy = pk_mul(dy, dy);
            const vf2 zz = pk_mul(dz, dz);
            vf2 s = pk_add(xx, yy);                // ((x^2+y^2)+z^2) order
            s = pk_add(s, zz);
            vf2 d;
            d.x = fminf(dd[p].x, s.x);
            d.y = fminf(dd[p].y, s.y);
            dd[p] = d;
            m0 = fmaxf(m0, d.x);
            m1 = fmaxf(m1, d.y);
        }
        const float bv = fmaxf(m0, m1);

        // reverse scan: lowest j with dd[j] == bv (exact compare; max is
        // rounding-free so bv equals at least one element)
        int bj = 0;
#pragma unroll
        for (int j = 7; j >= 0; j--) {
            const float v = (j & 1) ? dd[j >> 1].y : dd[j >> 1].x;
            if (v == bv) bj = j;
        }

        // global point index n = tid + bj*512; low key = 4095 - n
        const unsigned n = (unsigned)(tid + (bj << 9));
        unsigned long long key =
            ((unsigned long long)__float_as_uint(bv) << 32) |
            (unsigned long long)(4095u - n);

        key = wave_kmax63(key);
        const int par = i & 1;
        if (lane == 63) ckey[par][wid] = key;
        __syncthreads();

        // all threads redundantly resolve the 8-way final (no 2nd barrier:
        // parity double-buffer makes the next write race-free)
        const ulonglong2* kb = (const ulonglong2*)(&ckey[par][0]);
        const ulonglong2 a0 = kb[0], a1 = kb[1], a2 = kb[2], a3 = kb[3];
        const unsigned long long q0 = kmax2(a0.x, a0.y);
        const unsigned long long q1 = kmax2(a1.x, a1.y);
        const unsigned long long q2 = kmax2(a2.x, a2.y);
        const unsigned long long q3 = kmax2(a3.x, a3.y);
        const unsigned long long kk = kmax2(kmax2(q0, q1), kmax2(q2, q3));

        ci = (int)(4095u - (unsigned)kk);
        const float4 c = sp[ci];
        cx = c.x; cy = c.y; cz = c.z;
    }
    __syncthreads();

    // epilogue: coalesced writes of cents + vertices_pool
    for (int i = tid; i < NPOINT; i += FPS_T) {
        const int cc = scent[i];
        const float4 v = sp[cc];
        cents[b * NPOINT + i] = cc;
        out_vp[(b * 3 + 0) * NPOINT + i] = v.x;
        out_vp[(b * 3 + 1) * NPOINT + i] = v.y;
        out_vp[(b * 3 + 2) * NPOINT + i] = v.z;
    }
}

// ---------------------------------------------------------------------------
// Kernel 3: gather+maxpool selected rows AND transpose to (B, C, NPOINT).
// 16 waves per block; wave w pools point j0+w (64 lanes x float2 = 128 ch),
// stages the 16x128 tile in LDS, then writes channel-major 64B segments.
// ---------------------------------------------------------------------------
#define GT_J 16
__global__ __launch_bounds__(1024) void pool_gather_t(
        const float* __restrict__ fmT,     // (B*N, C)
        const int* __restrict__ idx,       // (B*N*K), values in [0, B*N)
        const int* __restrict__ cents,     // (B*NPOINT)
        float* __restrict__ out_fp)        // (B, C, NPOINT)
{
    __shared__ float tile[C_SZ][GT_J + 1];
    const int tid  = threadIdx.x;
    const int lane = tid & 63;
    const int w    = tid >> 6;
    const int j0   = blockIdx.x * GT_J;    // global pooled-point base
    const int gp   = j0 + w;
    const int b    = gp >> 10;             // NPOINT = 1024
    const int ci   = cents[gp];
    const int* ip  = idx + ((size_t)(b * N_SZ + ci)) * K_SZ;
    const float2* src = (const float2*)fmT;

    float2 acc = make_float2(-INFINITY, -INFINITY);
#pragma unroll
    for (int k = 0; k < K_SZ; k++) {
        const int p = ip[k];
        const float2 v = src[(size_t)p * (C_SZ / 2) + lane];
        acc.x = fmaxf(acc.x, v.x);
        acc.y = fmaxf(acc.y, v.y);
    }
    tile[2 * lane][w]     = acc.x;
    tile[2 * lane + 1][w] = acc.y;
    __syncthreads();

    float* q = out_fp + (size_t)b * C_SZ * NPOINT + (j0 & (NPOINT - 1));
#pragma unroll
    for (int it = 0; it < 2; it++) {
        const int e  = tid + it * 1024;
        const int c  = e >> 4;
        const int jj = e & (GT_J - 1);
        q[(size_t)c * NPOINT + jj] = tile[c][jj];
    }
}

// ---------------------------------------------------------------------------
extern "C" void kernel_launch(void* const* d_in, const int* in_sizes, int n_in,
                              void* d_out, int out_size, void* d_ws, size_t ws_size,
                              hipStream_t stream) {
    const float* verts = (const float*)d_in[0];   // (B,3,N) f32
    const float* fm    = (const float*)d_in[1];   // (B,C,N) f32
    const int*   idx   = (const int*)d_in[2];     // (B*N*K) i32

    float* out    = (float*)d_out;
    float* out_vp = out;                               // B*3*NPOINT = 24576
    float* out_fp = out + (size_t)B_SZ * 3 * NPOINT;   // B*C*NPOINT

    char* ws = (char*)d_ws;
    float* fmT   = (float*)ws;                                     // 16 MB
    int*   cents = (int*)(ws + (size_t)B_SZ * N_SZ * C_SZ * 4);    // 32 KB

    dim3 tb(32, 8);
    transpose_fm<<<dim3(N_SZ / 32, C_SZ / 32, B_SZ), tb, 0, stream>>>(fm, fmT);
    fps_kernel<<<B_SZ, FPS_T, 0, stream>>>(verts, out_vp, cents);
    pool_gather_t<<<(B_SZ * NPOINT) / GT_J, 1024, 0, stream>>>(fmT, idx, cents, out_fp);
}

// Round 7
// 643.481 us; speedup vs baseline: 1.2697x; 1.1789x over previous
//
#include <hip/hip_runtime.h>
#include <hip/hip_bf16.h>
#include <math.h>

// Problem constants
#define B_SZ 8
#define N_SZ 4096
#define C_SZ 128
#define K_SZ 16
#define NPOINT 1024            // N / POOL_RATE

// FPS config: 256 threads (4 waves, 1 per SIMD), 16 points per thread
#define FPS_T 256
#define FPS_PAIRS 8            // 8 float2-pairs = 16 points per thread

typedef float vf2 __attribute__((ext_vector_type(2)));

// ---------------------------------------------------------------------------
// Wave64 argmax via a u64-key DPP max chain, with the max done as v_max_f64:
// key = (dist_bits << 32) | (4095 - n). dist_bits <= bits(1e10)=0x501502F9,
// so the f64 view is positive, finite, non-NaN => f64 ordering == u64
// ordering (IEEE monotone bit trick). max key == max dist, min n on ties.
// bound_ctrl=1 feeds 0 (+0.0) into invalid lanes — never beats a real key.
// After row_shr 1/2/4/8 + row_bcast 15/31, lane 63 holds the wave max.
// ---------------------------------------------------------------------------
template <int CTRL>
__device__ __forceinline__ double dpp_dmax_step(double k) {
    const unsigned long long u = __builtin_bit_cast(unsigned long long, k);
    const int lo = (int)(unsigned)u;
    const int hi = (int)(unsigned)(u >> 32);
    const unsigned lo2 = (unsigned)__builtin_amdgcn_update_dpp(0, lo, CTRL, 0xF, 0xF, true);
    const unsigned hi2 = (unsigned)__builtin_amdgcn_update_dpp(0, hi, CTRL, 0xF, 0xF, true);
    const double k2 = __builtin_bit_cast(double,
        ((unsigned long long)hi2 << 32) | (unsigned long long)lo2);
    return fmax(k, k2);               // v_max_f64; operands never NaN
}
__device__ __forceinline__ double wave_dmax63(double k) {
    k = dpp_dmax_step<0x111>(k);  // row_shr:1
    k = dpp_dmax_step<0x112>(k);  // row_shr:2
    k = dpp_dmax_step<0x114>(k);  // row_shr:4
    k = dpp_dmax_step<0x118>(k);  // row_shr:8
    k = dpp_dmax_step<0x142>(k);  // row_bcast:15
    k = dpp_dmax_step<0x143>(k);  // row_bcast:31
    return k;
}

// ---------------------------------------------------------------------------
// Kernel 1: transpose feature_map (B, C, N) -> fmT (B*N, C)
// ---------------------------------------------------------------------------
__global__ void transpose_fm(const float* __restrict__ fm, float* __restrict__ fmT) {
    __shared__ float tile[32][33];
    const int b  = blockIdx.z;
    const int c0 = blockIdx.y * 32;
    const int n0 = blockIdx.x * 32;
    const int tx = threadIdx.x;   // 0..31
    const int ty = threadIdx.y;   // 0..7
    const float* p = fm + (size_t)b * C_SZ * N_SZ;
#pragma unroll
    for (int i = 0; i < 4; i++) {
        tile[ty + i * 8][tx] = p[(size_t)(c0 + ty + i * 8) * N_SZ + n0 + tx];
    }
    __syncthreads();
    float* q = fmT + (size_t)b * N_SZ * C_SZ;
#pragma unroll
    for (int i = 0; i < 4; i++) {
        q[(size_t)(n0 + ty + i * 8) * C_SZ + c0 + tx] = tile[tx][ty + i * 8];
    }
}

// ---------------------------------------------------------------------------
// Kernel 2: FPS, one block (256 threads, 4 waves — one per SIMD) per batch.
// Bit-exact numpy semantics: d=((x-cx)^2+(y-cy)^2)+(z-cz)^2 per-op rounding
// (contract/reassoc off), min then first-index argmax. One barrier per iter;
// f64-keyed DPP argmax; argmax index recovered by a post-loop reverse scan
// (keeps lowest index on ties). No global traffic in the loop.
// Tail LDS budget per iter: 4x ds_write_b64 + 4 waves x 2 ds_read_b128
// (ckey) + 4x ds_read_b128 (sp[ci]) ~= 12 b128-equivalents (~150 cyc),
// vs ~40 at 512 threads — the R6 bottleneck.
// ---------------------------------------------------------------------------
__global__ __launch_bounds__(FPS_T) void fps_kernel(
        const float* __restrict__ verts,   // (B, 3, N)
        float* __restrict__ out_vp,        // (B, 3, NPOINT)
        int* __restrict__ cents)           // (B, NPOINT)
{
#pragma clang fp contract(off)
#pragma clang fp reassociate(off)
    __shared__ float4 sp[N_SZ];                       // 64 KB xyz (w unused)
    __shared__ int    scent[NPOINT];                  //  4 KB
    __shared__ alignas(16) double ckey[2][4];

    const int b    = blockIdx.x;
    const int tid  = threadIdx.x;
    const int lane = tid & 63;
    const int wid  = tid >> 6;
    const float* vb = verts + (size_t)b * 3 * N_SZ;

    // pair p covers global points n = tid + (2p)*256 and n + 256
    vf2 px[FPS_PAIRS], py[FPS_PAIRS], pz[FPS_PAIRS], dd[FPS_PAIRS];
#pragma unroll
    for (int p = 0; p < FPS_PAIRS; p++) {
        const int n0 = tid + (2 * p) * FPS_T;
        const int n1 = n0 + FPS_T;
        const float x0 = vb[n0],            x1 = vb[n1];
        const float y0 = vb[N_SZ + n0],     y1 = vb[N_SZ + n1];
        const float z0 = vb[2 * N_SZ + n0], z1 = vb[2 * N_SZ + n1];
        px[p] = (vf2){x0, x1};
        py[p] = (vf2){y0, y1};
        pz[p] = (vf2){z0, z1};
        dd[p] = (vf2){1e10f, 1e10f};
        sp[n0] = make_float4(x0, y0, z0, 0.0f);
        sp[n1] = make_float4(x1, y1, z1, 0.0f);
    }
    __syncthreads();

    int ci = 0;
    float4 c0 = sp[0];
    float cx = c0.x, cy = c0.y, cz = c0.z;

    for (int i = 0; i < NPOINT; i++) {
        if (tid == 0) scent[i] = ci;

        const vf2 cx2 = (vf2){cx, cx};
        const vf2 cy2 = (vf2){cy, cy};
        const vf2 cz2 = (vf2){cz, cz};

        float m0 = -1.0f, m1 = -1.0f;      // running max (two halves)
#pragma unroll
        for (int p = 0; p < FPS_PAIRS; p++) {
            const vf2 dx = px[p] - cx2;
            const vf2 dy = py[p] - cy2;
            const vf2 dz = pz[p] - cz2;
            vf2 s = dx * dx + dy * dy;     // contract off => mul,mul,add
            s = s + dz * dz;               // ((x^2+y^2)+z^2) order
            vf2 d;
            d.x = fminf(dd[p].x, s.x);
            d.y = fminf(dd[p].y, s.y);
            dd[p] = d;
            m0 = fmaxf(m0, d.x);
            m1 = fmaxf(m1, d.y);
        }
        const float bv = fmaxf(m0, m1);

        // reverse scan: lowest j with dd[j] == bv (min/max are selections,
        // all dists are +0-or-positive normals => bitwise-exact compare)
        int bj = 0;
#pragma unroll
        for (int j = 15; j >= 0; j--) {
            const float v = (j & 1) ? dd[j >> 1].y : dd[j >> 1].x;
            if (v == bv) bj = j;
        }

        // global point index n = tid + bj*256; low key = 4095 - n
        const unsigned n = (unsigned)(tid + (bj << 8));
        double key = __builtin_bit_cast(double,
            ((unsigned long long)__float_as_uint(bv) << 32) |
            (unsigned long long)(4095u - n));

        key = wave_dmax63(key);
        const int par = i & 1;
        if (lane == 63) ckey[par][wid] = key;
        __syncthreads();

        // all threads redundantly resolve the 4-way final (no 2nd barrier:
        // parity double-buffer makes the next write race-free)
        const double2* kb = (const double2*)(&ckey[par][0]);
        const double2 k01 = kb[0], k23 = kb[1];
        const double kk = fmax(fmax(k01.x, k01.y), fmax(k23.x, k23.y));

        ci = (int)(4095u - (unsigned)__builtin_bit_cast(unsigned long long, kk));
        const float4 c = sp[ci];
        cx = c.x; cy = c.y; cz = c.z;
    }
    __syncthreads();

    // epilogue: coalesced writes of cents + vertices_pool
    for (int i = tid; i < NPOINT; i += FPS_T) {
        const int cc = scent[i];
        const float4 v = sp[cc];
        cents[b * NPOINT + i] = cc;
        out_vp[(b * 3 + 0) * NPOINT + i] = v.x;
        out_vp[(b * 3 + 1) * NPOINT + i] = v.y;
        out_vp[(b * 3 + 2) * NPOINT + i] = v.z;
    }
}

// ---------------------------------------------------------------------------
// Kernel 3: gather+maxpool selected rows AND transpose to (B, C, NPOINT).
// 16 waves per block; wave w pools point j0+w (64 lanes x float2 = 128 ch),
// stages the 16x128 tile in LDS, then writes channel-major 64B segments.
// ---------------------------------------------------------------------------
#define GT_J 16
__global__ __launch_bounds__(1024) void pool_gather_t(
        const float* __restrict__ fmT,     // (B*N, C)
        const int* __restrict__ idx,       // (B*N*K), values in [0, B*N)
        const int* __restrict__ cents,     // (B*NPOINT)
        float* __restrict__ out_fp)        // (B, C, NPOINT)
{
    __shared__ float tile[C_SZ][GT_J + 1];
    const int tid  = threadIdx.x;
    const int lane = tid & 63;
    const int w    = tid >> 6;
    const int j0   = blockIdx.x * GT_J;    // global pooled-point base
    const int gp   = j0 + w;
    const int b    = gp >> 10;             // NPOINT = 1024
    const int ci   = cents[gp];
    const int* ip  = idx + ((size_t)(b * N_SZ + ci)) * K_SZ;
    const float2* src = (const float2*)fmT;

    float2 acc = make_float2(-INFINITY, -INFINITY);
#pragma unroll
    for (int k = 0; k < K_SZ; k++) {
        const int p = ip[k];
        const float2 v = src[(size_t)p * (C_SZ / 2) + lane];
        acc.x = fmaxf(acc.x, v.x);
        acc.y = fmaxf(acc.y, v.y);
    }
    tile[2 * lane][w]     = acc.x;
    tile[2 * lane + 1][w] = acc.y;
    __syncthreads();

    float* q = out_fp + (size_t)b * C_SZ * NPOINT + (j0 & (NPOINT - 1));
#pragma unroll
    for (int it = 0; it < 2; it++) {
        const int e  = tid + it * 1024;
        const int c  = e >> 4;
        const int jj = e & (GT_J - 1);
        q[(size_t)c * NPOINT + jj] = tile[c][jj];
    }
}

// ---------------------------------------------------------------------------
extern "C" void kernel_launch(void* const* d_in, const int* in_sizes, int n_in,
                              void* d_out, int out_size, void* d_ws, size_t ws_size,
                              hipStream_t stream) {
    const float* verts = (const float*)d_in[0];   // (B,3,N) f32
    const float* fm    = (const float*)d_in[1];   // (B,C,N) f32
    const int*   idx   = (const int*)d_in[2];     // (B*N*K) i32

    float* out    = (float*)d_out;
    float* out_vp = out;                               // B*3*NPOINT = 24576
    float* out_fp = out + (size_t)B_SZ * 3 * NPOINT;   // B*C*NPOINT

    char* ws = (char*)d_ws;
    float* fmT   = (float*)ws;                                     // 16 MB
    int*   cents = (int*)(ws + (size_t)B_SZ * N_SZ * C_SZ * 4);    // 32 KB

    dim3 tb(32, 8);
    transpose_fm<<<dim3(N_SZ / 32, C_SZ / 32, B_SZ), tb, 0, stream>>>(fm, fmT);
    fps_kernel<<<B_SZ, FPS_T, 0, stream>>>(verts, out_vp, cents);
    pool_gather_t<<<(B_SZ * NPOINT) / GT_J, 1024, 0, stream>>>(fmT, idx, cents, out_fp);
}

// Round 8
// 612.150 us; speedup vs baseline: 1.3347x; 1.0512x over previous
//
#include <hip/hip_runtime.h>
#include <hip/hip_bf16.h>
#include <math.h>

// Problem constants
#define B_SZ 8
#define N_SZ 4096
#define C_SZ 128
#define K_SZ 16
#define NPOINT 1024            // N / POOL_RATE

// FPS config: 256 threads (4 waves, 1 per SIMD), 16 CONTIGUOUS points/thread
#define FPS_T 256
#define FPS_PAIRS 8            // 8 float2-pairs = 16 points per thread

typedef float vf2 __attribute__((ext_vector_type(2)));

// ---------------------------------------------------------------------------
// Wave64 f32 max chain via DPP (full-rate, ~2cyc/stage issue).
// bound_ctrl=1 feeds 0.0 into invalid lanes — distances are >= 0 so 0 is a
// safe identity. After row_shr 1/2/4/8 + row_bcast 15/31, lane 63 = wave max.
// ---------------------------------------------------------------------------
template <int CTRL>
__device__ __forceinline__ float dpp_fmax(float x) {
    int t = __builtin_amdgcn_update_dpp(0, __float_as_int(x), CTRL, 0xF, 0xF, true);
    return fmaxf(x, __int_as_float(t));
}
__device__ __forceinline__ float wave_fmax63(float x) {
    x = dpp_fmax<0x111>(x);  // row_shr:1
    x = dpp_fmax<0x112>(x);  // row_shr:2
    x = dpp_fmax<0x114>(x);  // row_shr:4
    x = dpp_fmax<0x118>(x);  // row_shr:8
    x = dpp_fmax<0x142>(x);  // row_bcast:15
    x = dpp_fmax<0x143>(x);  // row_bcast:31
    return x;                 // valid in lane 63
}
__device__ __forceinline__ unsigned long long kmax2(unsigned long long a,
                                                   unsigned long long b) {
    return a > b ? a : b;
}

// ---------------------------------------------------------------------------
// Kernel 1: transpose feature_map (B, C, N) -> fmT (B*N, C)
// ---------------------------------------------------------------------------
__global__ void transpose_fm(const float* __restrict__ fm, float* __restrict__ fmT) {
    __shared__ float tile[32][33];
    const int b  = blockIdx.z;
    const int c0 = blockIdx.y * 32;
    const int n0 = blockIdx.x * 32;
    const int tx = threadIdx.x;   // 0..31
    const int ty = threadIdx.y;   // 0..7
    const float* p = fm + (size_t)b * C_SZ * N_SZ;
#pragma unroll
    for (int i = 0; i < 4; i++) {
        tile[ty + i * 8][tx] = p[(size_t)(c0 + ty + i * 8) * N_SZ + n0 + tx];
    }
    __syncthreads();
    float* q = fmT + (size_t)b * N_SZ * C_SZ;
#pragma unroll
    for (int i = 0; i < 4; i++) {
        q[(size_t)(n0 + ty + i * 8) * C_SZ + c0 + tx] = tile[tx][ty + i * 8];
    }
}

// ---------------------------------------------------------------------------
// Kernel 2: FPS, one block (256 threads, 4 waves — one per SIMD) per batch.
// Bit-exact numpy semantics: d=((x-cx)^2+(y-cy)^2)+(z-cz)^2 per-op rounding
// (contract/reassoc off), min then FIRST-index argmax.
//
// Layout: thread tid owns contiguous points [tid*16, tid*16+16). Hence
// within a wave, lane order == point-index order, so the wave argmax is:
//   f32 DPP max chain -> readlane(63) -> ballot(bv==wmax) -> s_ff1 ->
//   readlane(n, first_lane)   (min n among ties, exact)
// Per-lane reverse scan gives min j (= min n) within the lane.
// Cross-wave: packed u64 key (dist<<32)|(4095-n), max => max dist, min n.
// One barrier per iteration; no global traffic in the loop.
// ---------------------------------------------------------------------------
__global__ __launch_bounds__(FPS_T) void fps_kernel(
        const float* __restrict__ verts,   // (B, 3, N)
        float* __restrict__ out_vp,        // (B, 3, NPOINT)
        int* __restrict__ cents)           // (B, NPOINT)
{
#pragma clang fp contract(off)
#pragma clang fp reassociate(off)
    __shared__ float4 sp[N_SZ];                       // 64 KB xyz (w unused)
    __shared__ int    scent[NPOINT];                  //  4 KB
    __shared__ alignas(16) unsigned long long ckey[2][4];

    const int b    = blockIdx.x;
    const int tid  = threadIdx.x;
    const int lane = tid & 63;
    const int wid  = tid >> 6;
    const float* vb = verts + (size_t)b * 3 * N_SZ;

    // stage xyz into LDS (coalesced global loads, conflict-free LDS writes)
    for (int n = tid; n < N_SZ; n += FPS_T) {
        sp[n] = make_float4(vb[n], vb[N_SZ + n], vb[2 * N_SZ + n], 0.0f);
    }

    // contiguous per-thread register copy via coalesced float4 loads
    const float4* vx4 = (const float4*)vb;
    const float4* vy4 = (const float4*)(vb + N_SZ);
    const float4* vz4 = (const float4*)(vb + 2 * N_SZ);
    vf2 px[FPS_PAIRS], py[FPS_PAIRS], pz[FPS_PAIRS], dd[FPS_PAIRS];
#pragma unroll
    for (int k = 0; k < 4; k++) {
        const float4 x = vx4[tid * 4 + k];
        const float4 y = vy4[tid * 4 + k];
        const float4 z = vz4[tid * 4 + k];
        px[2 * k] = (vf2){x.x, x.y}; px[2 * k + 1] = (vf2){x.z, x.w};
        py[2 * k] = (vf2){y.x, y.y}; py[2 * k + 1] = (vf2){y.z, y.w};
        pz[2 * k] = (vf2){z.x, z.y}; pz[2 * k + 1] = (vf2){z.z, z.w};
        dd[2 * k]     = (vf2){1e10f, 1e10f};
        dd[2 * k + 1] = (vf2){1e10f, 1e10f};
    }
    __syncthreads();

    int ci = 0;
    const float4 c0 = sp[0];
    float cx = c0.x, cy = c0.y, cz = c0.z;

    for (int i = 0; i < NPOINT; i++) {
        if (tid == 0) scent[i] = ci;

        const vf2 cx2 = (vf2){cx, cx};
        const vf2 cy2 = (vf2){cy, cy};
        const vf2 cz2 = (vf2){cz, cz};

        float m = -1.0f;                   // running max (v_max3 per pair)
#pragma unroll
        for (int p = 0; p < FPS_PAIRS; p++) {
            const vf2 dx = px[p] - cx2;
            const vf2 dy = py[p] - cy2;
            const vf2 dz = pz[p] - cz2;
            vf2 s = dx * dx + dy * dy;     // contract off => mul,mul,add
            s = s + dz * dz;               // ((x^2+y^2)+z^2) order
            vf2 d;
            d.x = fminf(dd[p].x, s.x);
            d.y = fminf(dd[p].y, s.y);
            dd[p] = d;
            m = fmaxf(m, fmaxf(d.x, d.y)); // folds to v_max3_f32
        }
        const float bv = m;

        // reverse scan: lowest j with dd[j] == bv (max is a selection =>
        // exact bitwise compare); n = tid*16 + j so min j == min n in-lane
        int bj = 0;
#pragma unroll
        for (int j = 15; j >= 0; j--) {
            const float v = (j & 1) ? dd[j >> 1].y : dd[j >> 1].x;
            if (v == bv) bj = j;
        }
        const int bn = (tid << 4) | bj;    // global point index

        // wave argmax: f32 chain + ballot + first-lane readback
        const float wm = wave_fmax63(bv);
        const float wmax = __int_as_float(
            __builtin_amdgcn_readlane(__float_as_int(wm), 63));
        const unsigned long long mask = __ballot(bv == wmax);
        const int first = __ffsll(mask) - 1;
        const unsigned nw = (unsigned)__builtin_amdgcn_readlane(bn, first);

        const unsigned long long wkey =
            ((unsigned long long)__float_as_uint(wmax) << 32) |
            (unsigned long long)(4095u - nw);

        const int par = i & 1;
        if (lane == 0) ckey[par][wid] = wkey;
        __syncthreads();

        // all threads redundantly resolve the 4-way final (no 2nd barrier:
        // parity double-buffer makes the next write race-free)
        const ulonglong2* kb = (const ulonglong2*)(&ckey[par][0]);
        const ulonglong2 k01 = kb[0], k23 = kb[1];
        const unsigned long long kk =
            kmax2(kmax2(k01.x, k01.y), kmax2(k23.x, k23.y));

        ci = (int)(4095u - (unsigned)kk);
        const float4 c = sp[ci];
        cx = c.x; cy = c.y; cz = c.z;
    }
    __syncthreads();

    // epilogue: coalesced writes of cents + vertices_pool
    for (int i = tid; i < NPOINT; i += FPS_T) {
        const int cc = scent[i];
        const float4 v = sp[cc];
        cents[b * NPOINT + i] = cc;
        out_vp[(b * 3 + 0) * NPOINT + i] = v.x;
        out_vp[(b * 3 + 1) * NPOINT + i] = v.y;
        out_vp[(b * 3 + 2) * NPOINT + i] = v.z;
    }
}

// ---------------------------------------------------------------------------
// Kernel 3: gather+maxpool selected rows AND transpose to (B, C, NPOINT).
// 16 waves per block; wave w pools point j0+w (64 lanes x float2 = 128 ch),
// stages the 16x128 tile in LDS, then writes channel-major 64B segments.
// ---------------------------------------------------------------------------
#define GT_J 16
__global__ __launch_bounds__(1024) void pool_gather_t(
        const float* __restrict__ fmT,     // (B*N, C)
        const int* __restrict__ idx,       // (B*N*K), values in [0, B*N)
        const int* __restrict__ cents,     // (B*NPOINT)
        float* __restrict__ out_fp)        // (B, C, NPOINT)
{
    __shared__ float tile[C_SZ][GT_J + 1];
    const int tid  = threadIdx.x;
    const int lane = tid & 63;
    const int w    = tid >> 6;
    const int j0   = blockIdx.x * GT_J;    // global pooled-point base
    const int gp   = j0 + w;
    const int b    = gp >> 10;             // NPOINT = 1024
    const int ci   = cents[gp];
    const int* ip  = idx + ((size_t)(b * N_SZ + ci)) * K_SZ;
    const float2* src = (const float2*)fmT;

    float2 acc = make_float2(-INFINITY, -INFINITY);
#pragma unroll
    for (int k = 0; k < K_SZ; k++) {
        const int p = ip[k];
        const float2 v = src[(size_t)p * (C_SZ / 2) + lane];
        acc.x = fmaxf(acc.x, v.x);
        acc.y = fmaxf(acc.y, v.y);
    }
    tile[2 * lane][w]     = acc.x;
    tile[2 * lane + 1][w] = acc.y;
    __syncthreads();

    float* q = out_fp + (size_t)b * C_SZ * NPOINT + (j0 & (NPOINT - 1));
#pragma unroll
    for (int it = 0; it < 2; it++) {
        const int e  = tid + it * 1024;
        const int c  = e >> 4;
        const int jj = e & (GT_J - 1);
        q[(size_t)c * NPOINT + jj] = tile[c][jj];
    }
}

// ---------------------------------------------------------------------------
extern "C" void kernel_launch(void* const* d_in, const int* in_sizes, int n_in,
                              void* d_out, int out_size, void* d_ws, size_t ws_size,
                              hipStream_t stream) {
    const float* verts = (const float*)d_in[0];   // (B,3,N) f32
    const float* fm    = (const float*)d_in[1];   // (B,C,N) f32
    const int*   idx   = (const int*)d_in[2];     // (B*N*K) i32

    float* out    = (float*)d_out;
    float* out_vp = out;                               // B*3*NPOINT = 24576
    float* out_fp = out + (size_t)B_SZ * 3 * NPOINT;   // B*C*NPOINT

    char* ws = (char*)d_ws;
    float* fmT   = (float*)ws;                                     // 16 MB
    int*   cents = (int*)(ws + (size_t)B_SZ * N_SZ * C_SZ * 4);    // 32 KB

    dim3 tb(32, 8);
    transpose_fm<<<dim3(N_SZ / 32, C_SZ / 32, B_SZ), tb, 0, stream>>>(fm, fmT);
    fps_kernel<<<B_SZ, FPS_T, 0, stream>>>(verts, out_vp, cents);
    pool_gather_t<<<(B_SZ * NPOINT) / GT_J, 1024, 0, stream>>>(fmT, idx, cents, out_fp);
}